// Round 9
// baseline (93.819 us; speedup 1.0000x reference)
//
#include <hip/hip_runtime.h>

// PiecewisePolynomial: out[b,o] = sum_i sum_j L_j(x_in(b,i)) * w[o, i, 3*seg(b,i)+j]
// B=512, IN_F=256, OUT_F=256, SEGMENTS=16, N=4 (nodes -1,-0.5,0.5,1)
//
// R9: wave-uniform gather. pp_prep builds (a) we[i][s][o] f16x4 (8.4MB) and
// (b) basis table bt[b][i]={cA,cB,seg,0} (2MB). pp_main: lane=o, (b,i)
// wave-uniform -> seg uniform -> LDS weight reads are CONTIGUOUS ds_read_b64
// (no multi-address gather), basis via scalar-pipe s_load. Stage via pure
// 16B global_load_lds (global layout == LDS layout). Partials + reduce.

typedef _Float16 h2 __attribute__((ext_vector_type(2)));

#define INF     256
#define OUTF    256
#define WSTRIDE 49
#define OSTRIDE (INF * WSTRIDE)       // 12544
#define PSLICE  (512 * 256)           // floats per isplit slice (32 slices)
#define WE_U2   (256 * 16 * 256)      // uint2 count = 8.4 MB
#define BT_U4   (512 * 256)           // uint4 count = 2 MB

#define GLOAD16(gptr, lptr)                                                         \
  __builtin_amdgcn_global_load_lds(                                                 \
      (const __attribute__((address_space(1))) unsigned int*)(gptr),                \
      (__attribute__((address_space(3))) unsigned int*)(lptr), 16, 0, 0)

// ---- prep: blocks 0..255 expand w -> we[i][s][o] (coalesced o-writes);
//      blocks 256..383 build bt[b][i] = {cA,cB,seg,0} ----
__global__ __launch_bounds__(256)
void pp_prep(const float* __restrict__ x, const float* __restrict__ w,
             uint2* __restrict__ we, uint4* __restrict__ bt) {
    const int blk = blockIdx.x;
    if (blk < 256) {
        const int i = blk, o = threadIdx.x;
        const float* src = w + (size_t)o * OSTRIDE + i * WSTRIDE;
        float t[49];
        #pragma unroll
        for (int k = 0; k < 49; ++k) t[k] = src[k];
        #pragma unroll
        for (int s = 0; s < 16; ++s) {
            auto p0 = __builtin_amdgcn_cvt_pkrtz(t[3*s],   t[3*s+1]);
            auto p1 = __builtin_amdgcn_cvt_pkrtz(t[3*s+2], t[3*s+3]);
            uint2 v;
            v.x = __builtin_bit_cast(unsigned int, p0);
            v.y = __builtin_bit_cast(unsigned int, p1);
            we[((size_t)i * 16 + s) * 256 + o] = v;     // consecutive o: coalesced
        }
    } else {
        const int e = (blk - 256) * 1024 + threadIdx.x * 4;   // (b*256 + i), 4 at a time
        float4 xv = *(const float4*)(x + e);                  // x[b][i0..i0+3]
        const float xs[4] = {xv.x, xv.y, xv.z, xv.w};
        #pragma unroll
        for (int q = 0; q < 4; ++q) {
            float xx = xs[q];
            int id = (int)((xx + 1.0f) * 8.0f);
            id = id < 0 ? 0 : (id > 15 ? 15 : id);
            float u = (xx - ((float)id * 0.125f - 1.0f)) * 16.0f - 1.0f;
            float a = u + 1.0f, b2 = u + 0.5f, cc = u - 0.5f, d = u - 1.0f;
            float c0 = b2 * cc * d  * (-2.0f / 3.0f);
            float c1 = a  * cc * d  * ( 4.0f / 3.0f);
            float c2 = a  * b2 * d  * (-4.0f / 3.0f);
            float c3 = a  * b2 * cc * ( 2.0f / 3.0f);
            auto pA = __builtin_amdgcn_cvt_pkrtz(c0, c1);
            auto pB = __builtin_amdgcn_cvt_pkrtz(c2, c3);
            uint4 v;
            v.x = __builtin_bit_cast(unsigned int, pA);
            v.y = __builtin_bit_cast(unsigned int, pB);
            v.z = (unsigned int)id;
            v.w = 0u;
            bt[e + q] = v;
        }
    }
}

// ---- main: grid (32 isplit, 4 otile, 4 btile-of-128) x 256 thr, 64KB LDS ----
__global__ __launch_bounds__(256, 2)
void pp_main(const uint2* __restrict__ we, const uint4* __restrict__ bt,
             float* __restrict__ part) {
    __shared__ uint2 wt[8192];     // [8 i][16 s][64 o] uint2 = 64 KB

    const int tid  = threadIdx.x;
    const int wave = __builtin_amdgcn_readfirstlane(tid >> 6);  // provably uniform
    const int lane = tid & 63;
    const int i_base = blockIdx.x * 8;
    const int o_base = blockIdx.y * 64;
    const int b0     = blockIdx.z * 128 + wave * 32;   // this wave's 32 b rows

    // ---- stage: 16x 16B glds per thread; global layout == LDS layout ----
    #pragma unroll
    for (int it = 0; it < 16; ++it) {
        const int u = it * 256 + tid;          // 16B unit 0..4095
        const int i = u >> 9, s = (u >> 5) & 15, g = u & 31;
        const unsigned int* gp = (const unsigned int*)we
            + ((((size_t)(i_base + i) * 16 + s) * 256) + o_base + g * 2) * 2;
        GLOAD16(gp, (unsigned int*)wt + (size_t)u * 4);
    }
    __syncthreads();

    // ---- compute: (b,i) wave-uniform -> s_load basis, contiguous ds_read_b64 --
    const uint4* btp = bt + ((size_t)b0 * 256 + i_base);
    float* pout = part + (size_t)blockIdx.x * PSLICE + o_base + lane;

    for (int bb = 0; bb < 32; ++bb) {
        const uint4* be = btp + (size_t)bb * 256;    // 8 consecutive entries
        float acc = 0.0f;
        #pragma unroll
        for (int i = 0; i < 8; ++i) {
            const uint4 B = be[i];                   // uniform addr -> s_load
            const h2 cA = __builtin_bit_cast(h2, B.x);
            const h2 cB = __builtin_bit_cast(h2, B.y);
            const uint2 wv = wt[((i * 16 + (int)B.z) << 6) + lane];  // contiguous
            acc = __builtin_amdgcn_fdot2(__builtin_bit_cast(h2, wv.x), cA, acc, false);
            acc = __builtin_amdgcn_fdot2(__builtin_bit_cast(h2, wv.y), cB, acc, false);
        }
        pout[(size_t)(b0 + bb) * 256] = acc;         // 64 lanes x 4B contiguous
    }
}

__global__ __launch_bounds__(256)
void pp_reduce(const float* __restrict__ part, float* __restrict__ out) {
    const size_t off4 = (size_t)blockIdx.x * 256 + threadIdx.x;  // float4 idx
    const float4* p4 = (const float4*)part;
    float4 s = make_float4(0.f, 0.f, 0.f, 0.f);
    #pragma unroll
    for (int k = 0; k < 32; ++k) {
        float4 v = p4[(size_t)k * (PSLICE / 4) + off4];
        s.x += v.x; s.y += v.y; s.z += v.z; s.w += v.w;
    }
    ((float4*)out)[off4] = s;
}

extern "C" void kernel_launch(void* const* d_in, const int* in_sizes, int n_in,
                              void* d_out, int out_size, void* d_ws, size_t ws_size,
                              hipStream_t stream) {
    const float* x = (const float*)d_in[0];
    const float* w = (const float*)d_in[1];
    float* out = (float*)d_out;
    uint2* we  = (uint2*)d_ws;                                        // 8.4 MB
    uint4* bt  = (uint4*)((char*)d_ws + (size_t)WE_U2 * 8);           // 2 MB
    float* part = (float*)((char*)d_ws + (size_t)WE_U2 * 8
                                       + (size_t)BT_U4 * 16);         // 16.8 MB
    (void)ws_size; (void)n_in; (void)in_sizes; (void)out_size;

    pp_prep<<<dim3(384), 256, 0, stream>>>(x, w, we, bt);
    pp_main<<<dim3(32, 4, 4), 256, 0, stream>>>(we, bt, part);
    pp_reduce<<<dim3(128), 256, 0, stream>>>(part, out);
}